// Round 7
// baseline (664.188 us; speedup 1.0000x reference)
//
#include <hip/hip_runtime.h>

typedef unsigned short u16;
typedef unsigned int u32;
typedef __attribute__((ext_vector_type(8))) short short8;
typedef __attribute__((ext_vector_type(4))) float floatx4;

__device__ __forceinline__ float bf2f(u16 x) {
    union { u32 u; float f; } c; c.u = ((u32)x) << 16; return c.f;
}
__device__ __forceinline__ u16 f2bf(float f) {
    union { float f; u32 u; } c; c.f = f;
    return (u16)((c.u + 0x7FFFu + ((c.u >> 16) & 1u)) >> 16);
}
// pack two f32 -> one u32 of 2x bf16 (RNE). Portable (no inline asm; per
// m240 the compiler schedules scalar casts better than hand-written cvt_pk).
__device__ __forceinline__ u32 pack_bf16(float lo, float hi) {
    return ((u32)f2bf(lo)) | (((u32)f2bf(hi)) << 16);
}

// async global->LDS, 16B per lane. LDS dest = wave-uniform base + lane*16.
#define GLD_LDS(g, l) __builtin_amdgcn_global_load_lds( \
    (const __attribute__((address_space(1))) u32*)(g),  \
    (__attribute__((address_space(3))) u32*)(l), 16, 0, 0)

// ---------------- f32 -> bf16 convert (optional fused relu) ----------------

__global__ void cvt_kernel(const float* __restrict__ src, u16* __restrict__ dst,
                           int n8, int do_relu) {
    int i = blockIdx.x * 256 + threadIdx.x;
    if (i >= n8) return;
    float4 a = ((const float4*)src)[2 * i];
    float4 b = ((const float4*)src)[2 * i + 1];
    float v[8] = {a.x, a.y, a.z, a.w, b.x, b.y, b.z, b.w};
    short8 o;
#pragma unroll
    for (int j = 0; j < 8; j++) {
        float x = v[j];
        if (do_relu) x = fmaxf(x, 0.f);
        o[j] = (short)f2bf(x);
    }
    ((short8*)dst)[i] = o;
}

// ---------------- stats / gates (pure f32) ----------------

// column mean over sequence: x [B,N,1024] f32 -> out [B*1024] f32 (pre-zeroed)
__global__ void mean_kernel(const float* __restrict__ x, float* __restrict__ out,
                            int N, int chunk) {
    int idx = blockIdx.x * 256 + threadIdx.x;   // (b,d) in [0, 8192)
    int b = idx >> 10, d = idx & 1023;
    int nlo = blockIdx.y * chunk;
    const float* p = x + (size_t)b * N * 1024 + (size_t)nlo * 1024 + d;
    float s = 0.f;
    for (int n = 0; n < chunk; n++) s += p[(size_t)n * 1024];
    atomicAdd(out + idx, s * (1.0f / (float)N));
}

// gate[b,n] = 1 + sigmoid( relu(mean[b,:]) . Wg[n,:] + bg[n] ), one wave/output
__global__ __launch_bounds__(256) void gate_kernel(const float* __restrict__ mean,
                                                   const float* __restrict__ Wg,
                                                   const float* __restrict__ bg,
                                                   float* __restrict__ gout) {
    int gw = blockIdx.x * 4 + (threadIdx.x >> 6);   // [0, 8192)
    int lane = threadIdx.x & 63;
    int b = gw >> 10, n = gw & 1023;
    const float* wr = Wg + (size_t)n * 1024;
    const float* mr = mean + b * 1024;
    float acc = 0.f;
    for (int k = lane; k < 1024; k += 64)
        acc += fmaxf(mr[k], 0.f) * wr[k];
#pragma unroll
    for (int m = 1; m < 64; m <<= 1) acc += __shfl_xor(acc, m, 64);
    if (lane == 0) {
        float xg = acc + bg[n];
        gout[gw] = 1.f + 1.f / (1.f + __expf(-xg));
    }
}

// ---------------- GEMM: C[M,N] = A[M,K] . W[N,K]^T + bias, optional (1+gate) ----------------
// A, W bf16 (pre-converted in ws). 128x128 tile, BK=32, 4 waves (2x2), each
// wave 4x4 MFMA 16x16x32. DOUBLE-BUFFERED GLD_LDS staging (T3 2-phase).
// XCD-aware bijective block swizzle (all grids nwg % 8 == 0).
// Output bf16 (Ch) or f32 (Cf), exactly one non-null.

__global__ __launch_bounds__(256) void gemm_bt_kernel(
    const u16* __restrict__ A, const u16* __restrict__ W,
    const float* __restrict__ bias, const float* __restrict__ gate,
    u16* __restrict__ Ch, float* __restrict__ Cf,
    int M, int N, int K, int seq, int gateN)
{
    __shared__ u16 As[2][128 * 32];   // [m][k] row-major, 2 x 8 KB
    __shared__ u16 Bs[2][128 * 32];   // [n][k] row-major, 2 x 8 KB

    const int tid = threadIdx.x;
    const int wave = tid >> 6, lane = tid & 63, quad = lane >> 4, l15 = lane & 15;

    // XCD swizzle: contiguous grid chunk per XCD (bijective since nwg%8==0)
    const u32 gx = gridDim.x;
    const u32 flat = blockIdx.y * gx + blockIdx.x;
    const u32 per = (gx * gridDim.y) >> 3;
    const u32 swz = (flat & 7) * per + (flat >> 3);
    const int m0 = (int)(swz / gx) * 128, n0 = (int)(swz % gx) * 128;

    const int wm = (wave >> 1) * 64, wn = (wave & 1) * 64;

    floatx4 acc[4][4] = {};

    // staging map: round r covers tile bytes [r*4096 + wave*1024 + lane*16, +16)
    const int e0 = (wave * 1024 + lane * 16) >> 1;       // elements, round 0
    const int sr0 = e0 >> 5, sc0 = e0 & 31;
    const int e1 = e0 + 2048;                            // round 1
    const int sr1 = e1 >> 5, sc1 = e1 & 31;
    const size_t aoff0 = (size_t)(m0 + sr0) * K + sc0;
    const size_t aoff1 = (size_t)(m0 + sr1) * K + sc1;
    const size_t boff0 = (size_t)(n0 + sr0) * K + sc0;
    const size_t boff1 = (size_t)(n0 + sr1) * K + sc1;

    // prologue: stage K-tile 0 into buffer 0
    GLD_LDS(A + aoff0, As[0] + wave * 512);
    GLD_LDS(A + aoff1, As[0] + 2048 + wave * 512);
    GLD_LDS(W + boff0, Bs[0] + wave * 512);
    GLD_LDS(W + boff1, Bs[0] + 2048 + wave * 512);
    __syncthreads();

    int cur = 0;
    for (int k0 = 0; k0 < K; k0 += 32) {
        const int nxt = cur ^ 1;
        // issue next tile's DMA early (hides under this tile's compute)
        if (k0 + 32 < K) {
            GLD_LDS(A + aoff0 + k0 + 32, As[nxt] + wave * 512);
            GLD_LDS(A + aoff1 + k0 + 32, As[nxt] + 2048 + wave * 512);
            GLD_LDS(W + boff0 + k0 + 32, Bs[nxt] + wave * 512);
            GLD_LDS(W + boff1 + k0 + 32, Bs[nxt] + 2048 + wave * 512);
        }

        short8 af[4], bfr[4];
#pragma unroll
        for (int i = 0; i < 4; i++) {
            af[i]  = *(const short8*)(As[cur] + (wm + i * 16 + l15) * 32 + quad * 8);
            bfr[i] = *(const short8*)(Bs[cur] + (wn + i * 16 + l15) * 32 + quad * 8);
        }
#pragma unroll
        for (int mi = 0; mi < 4; mi++)
#pragma unroll
            for (int ni = 0; ni < 4; ni++)
                acc[mi][ni] = __builtin_amdgcn_mfma_f32_16x16x32_bf16(af[mi], bfr[ni], acc[mi][ni], 0, 0, 0);
        __syncthreads();
        cur = nxt;
    }

    const int b = m0 / seq;
#pragma unroll
    for (int ni = 0; ni < 4; ni++) {
        const int ncol = n0 + wn + ni * 16 + l15;
        const float bsv = bias[ncol];
        float g = 1.f;
        if (gate != nullptr && ncol < gateN) g = gate[b * 1024 + (ncol & 1023)];
#pragma unroll
        for (int mi = 0; mi < 4; mi++) {
            const int row = m0 + wm + mi * 16 + quad * 4;
#pragma unroll
            for (int r = 0; r < 4; r++) {
                float val = (acc[mi][ni][r] + bsv) * g;
                size_t idx = (size_t)(row + r) * N + ncol;
                if (Cf) Cf[idx] = val; else Ch[idx] = f2bf(val);
            }
        }
    }
}

// ---------------- fused flash attention (+ fused residual epilogue) ----------------
// T: [B, N, 3072] bf16 gated trans (k | q | v thirds, 8 heads x 128 each).
// X: [B, N, 1024] f32 original input for the residual.
// U: [B, N, 1024] bf16 out = bf16(X + attn).
// Block = (128 q-rows, b*8+h), 512 threads / 8 waves, ONE 16-row group per
// wave -> per-wave VGPR halves vs the 4-wave version; __launch_bounds__(512,4)
// targets VGPR<=128 so TWO blocks fit per CU (16 waves, 4/SIMD).
// KVBLK=64, double-buffered K/V (T3) + issue-early/write-late V (T14).
// SWAPPED QK^T (T12): mfma(K,Q) puts P row-local to lane (q=l15); softmax
// row-reduce = in-reg tree + 2 shuffles; defer-max (T13, THR=8).
// Packed-P scratch lives in the wave's PRIVATE 2KB slice of Vs[nxt]
// (rows [16w,16w+16)): pack -> pf read -> PV(Vs[cur]) -> late V write
// overwrites the dead P. Race-free: region is wave-private, in-order per
// wave, PV reads only Vs[cur]. P words XOR-swizzled ^((l15&7)<<2)
// (carry-free: (A^X)+w == (A+w)^X since A,X have zero low bits).
// XCD swizzle: all qb-blocks of one (b,h) on one XCD's L2.

__global__ __launch_bounds__(512, 4) void attn_kernel(
    const u16* __restrict__ T, const float* __restrict__ X,
    u16* __restrict__ U, int N)
{
    __shared__ __align__(16) u16 Ks[2][64 * 128];  // 2 x 16 KB, swizzled [kv][d]
    __shared__ __align__(16) u16 Vs[2][128 * 64];  // 2 x 16 KB, swizzled [d][kv]

    const int tid = threadIdx.x;
    const int wave = tid >> 6, lane = tid & 63, quad = (lane >> 4) & 3, l15 = lane & 15;

    // XCD swizzle: assume flat-id round-robin over 8 XCDs; give each XCD
    // whole (b,h) groups so K/V stay in one L2. Bijective for gridY=64.
    const int f = blockIdx.y * gridDim.x + blockIdx.x;
    const int i3 = f >> 3;
    const int qb = i3 % gridDim.x;
    const int bh = (f & 7) * 8 + i3 / gridDim.x;
    const int b = bh >> 3, h = bh & 7;

    const size_t base = (size_t)b * N * 3072;
    const int kcol = h * 128, qcol = 1024 + h * 128, vcol = 2048 + h * 128;

    // Q fragments: this wave's 16 rows, row = qrow0 + l15
    short8 qf[4];
    const int qrow0 = qb * 128 + wave * 16;
#pragma unroll
    for (int c = 0; c < 4; c++)
        qf[c] = *(const short8*)(T + base + (size_t)(qrow0 + l15) * 3072
                                   + qcol + c * 32 + quad * 8);

    floatx4 o[8] = {};
    float mrow = -1e30f, lrow = 0.f;
    const float scale = 0.08838834764831845f;  // 1/sqrt(128)

    // K staging map: 2 rounds x (512 lanes x 16B) = 16 KB.
    // LDS byte ob holds K[kv = ob>>8][d = (((ob>>4)&15) ^ (kv&15))*8 .. +8)
    int kst_kv[2], kst_d[2];
#pragma unroll
    for (int r = 0; r < 2; r++) {
        int ob = r * 8192 + wave * 1024 + lane * 16;
        int kv = ob >> 8;
        kst_kv[r] = kv;
        kst_d[r] = ((((ob >> 4) & 15) ^ (kv & 15)) << 3);
    }
    // V staging: thread covers rows (vkv, vkv+1) x d-slice vd8*8..+7;
    // wave w writes exactly Vs rows [16w, 16w+16) = its private 2KB slice.
    const int vkv = (tid & 31) * 2;
    const int vd8 = tid >> 5;            // [0,16)

    // ---- prologue: stage tile 0 ----
    short8 v0, v1;
#pragma unroll
    for (int r = 0; r < 2; r++)
        GLD_LDS(T + base + (size_t)kst_kv[r] * 3072 + kcol + kst_d[r],
                Ks[0] + r * 4096 + wave * 512);
    {
        const u16* vp = T + base + (size_t)vkv * 3072 + vcol + vd8 * 8;
        v0 = *(const short8*)vp;
        v1 = *(const short8*)(vp + 3072);
    }
#pragma unroll
    for (int j = 0; j < 8; j++) {
        u32 wv = ((u32)(u16)v0[j]) | (((u32)(u16)v1[j]) << 16);
        *(u32*)((char*)Vs[0] + (size_t)(vd8 * 8 + j) * 128
                + ((((vkv >> 3) ^ j)) << 4) + ((vkv * 2) & 15)) = wv;
    }
    __syncthreads();

    int cur = 0;
    for (int kt = 0; kt < N; kt += 64) {
        const int nxt = cur ^ 1;
        const bool more = (kt + 64) < N;

        // ---- issue next tile's staging EARLY (hides under compute) ----
        if (more) {
#pragma unroll
            for (int r = 0; r < 2; r++)
                GLD_LDS(T + base + (size_t)(kt + 64 + kst_kv[r]) * 3072 + kcol + kst_d[r],
                        Ks[nxt] + r * 4096 + wave * 512);
            const u16* vp = T + base + (size_t)(kt + 64 + vkv) * 3072 + vcol + vd8 * 8;
            v0 = *(const short8*)vp;
            v1 = *(const short8*)(vp + 3072);
        }

        // ---- QK^T (swapped): p[ni][r] = P[q=l15][kv=ni*16+quad*4+r] ----
        float p[4][4];
        __builtin_amdgcn_s_setprio(1);
#pragma unroll
        for (int ni = 0; ni < 4; ni++) {
            short8 kf[4];
#pragma unroll
            for (int c = 0; c < 4; c++)
                kf[c] = *(const short8*)(Ks[cur] + (ni * 16 + l15) * 128
                                            + (((c * 4 + quad) ^ l15) << 3));
            floatx4 s = {0.f, 0.f, 0.f, 0.f};
#pragma unroll
            for (int c = 0; c < 4; c++)
                s = __builtin_amdgcn_mfma_f32_16x16x32_bf16(kf[c], qf[c], s, 0, 0, 0);
#pragma unroll
            for (int r = 0; r < 4; r++) p[ni][r] = s[r] * scale;
        }
        __builtin_amdgcn_s_setprio(0);

        // ---- online softmax, lane-local rows (q=l15), defer-max THR=8 ----
        {
            float tm = p[0][0];
#pragma unroll
            for (int ni = 0; ni < 4; ni++)
#pragma unroll
                for (int r = 0; r < 4; r++) tm = fmaxf(tm, p[ni][r]);
            tm = fmaxf(tm, __shfl_xor(tm, 16, 64));
            tm = fmaxf(tm, __shfl_xor(tm, 32, 64));
            const bool need = __any(tm > mrow + 8.f);   // wave-uniform
            if (need) {
                float mnew = fmaxf(mrow, tm);
                float alpha = __expf(mrow - mnew);
                mrow = mnew;
                float ps = 0.f;
#pragma unroll
                for (int ni = 0; ni < 4; ni++)
#pragma unroll
                    for (int r = 0; r < 4; r++) {
                        float pe = __expf(p[ni][r] - mnew);
                        p[ni][r] = pe;
                        ps += pe;
                    }
                ps += __shfl_xor(ps, 16, 64);
                ps += __shfl_xor(ps, 32, 64);
                lrow = lrow * alpha + ps;
#pragma unroll
                for (int r = 0; r < 4; r++) {
                    float ab = __shfl(alpha, quad * 4 + r, 64);
#pragma unroll
                    for (int nt = 0; nt < 8; nt++) o[nt][r] *= ab;
                }
            } else {
                float ps = 0.f;
#pragma unroll
                for (int ni = 0; ni < 4; ni++)
#pragma unroll
                    for (int r = 0; r < 4; r++) {
                        float pe = __expf(p[ni][r] - mrow);
                        p[ni][r] = pe;
                        ps += pe;
                    }
                ps += __shfl_xor(ps, 16, 64);
                ps += __shfl_xor(ps, 32, 64);
                lrow += ps;
            }
        }

        // ---- P pack into wave-private scratch (Vs[nxt] rows [16w,16w+16)) ----
        u32* pw = (u32*)((char*)Vs[nxt] + wave * 2048);
        const int xs = (l15 & 7) << 2;
#pragma unroll
        for (int ni = 0; ni < 4; ni++)
#pragma unroll
            for (int s2 = 0; s2 < 2; s2++)
                pw[l15 * 32 + ((ni * 8 + quad * 2 + s2) ^ xs)]
                    = pack_bf16(p[ni][2 * s2], p[ni][2 * s2 + 1]);
        short8 pf[2];
#pragma unroll
        for (int kc = 0; kc < 2; kc++)
            pf[kc] = *(const short8*)(pw + l15 * 32 + ((kc * 16 + quad * 4) ^ xs));

        // ---- PV: 16 MFMA, swizzled conflict-free V reads ----
        __builtin_amdgcn_s_setprio(1);
#pragma unroll
        for (int nt = 0; nt < 8; nt++) {
#pragma unroll
            for (int kc = 0; kc < 2; kc++) {
                short8 vf = *(const short8*)(Vs[cur] + (nt * 16 + l15) * 64
                                + (((kc * 4 + quad) ^ (l15 & 7)) << 3));
                o[nt] = __builtin_amdgcn_mfma_f32_16x16x32_bf16(pf[kc], vf, o[nt], 0, 0, 0);
            }
        }
        __builtin_amdgcn_s_setprio(0);

        // ---- late V write into own slice of Vs[nxt] (overwrites dead P) ----
        if (more) {
#pragma unroll
            for (int j = 0; j < 8; j++) {
                u32 wv = ((u32)(u16)v0[j]) | (((u32)(u16)v1[j]) << 16);
                *(u32*)((char*)Vs[nxt] + (size_t)(vd8 * 8 + j) * 128
                        + ((((vkv >> 3) ^ j)) << 4) + ((vkv * 2) & 15)) = wv;
            }
        }
        __syncthreads();
        cur = nxt;
    }

    // ---- epilogue: broadcast l, fuse residual: U = bf16(X + O/l) ----
    const size_t ub = (size_t)b * N * 1024;
#pragma unroll
    for (int r = 0; r < 4; r++) {
        float lb = __shfl(lrow, quad * 4 + r, 64);
        float inv = 1.f / lb;
        const size_t row = qb * 128 + wave * 16 + quad * 4 + r;
#pragma unroll
        for (int nt = 0; nt < 8; nt++) {
            const size_t idx = ub + row * 1024 + h * 128 + nt * 16 + l15;
            U[idx] = f2bf(X[idx] + o[nt][r] * inv);
        }
    }
}

// ---------------- launch ----------------
// Inputs f32, outputs f32 (both per reference dtypes). ws peak = 80.1 MB:
// stats 128 KB | weights 8 MB @1MB | activations 16 MB @16MB | trans 48 MB @32MB.
// q phase then v phase reuse the same regions sequentially. Residual add is
// fused into attn's epilogue (writes bf16(X + attn) into aReg, consumed by
// the output-proj GEMM).

extern "C" void kernel_launch(void* const* d_in, const int* in_sizes, int n_in,
                              void* d_out, int out_size, void* d_ws, size_t ws_size,
                              hipStream_t stream) {
    (void)in_sizes; (void)n_in; (void)out_size; (void)ws_size;
    const float* v   = (const float*)d_in[0];
    const float* q   = (const float*)d_in[1];
    const float* Wg_v4q = (const float*)d_in[2];
    const float* bg_v4q = (const float*)d_in[3];
    const float* Wg_q4v = (const float*)d_in[4];
    const float* bg_q4v = (const float*)d_in[5];
    const float* Wv  = (const float*)d_in[6];
    const float* bv  = (const float*)d_in[7];
    const float* Wq  = (const float*)d_in[8];
    const float* bq  = (const float*)d_in[9];
    const float* Wvo = (const float*)d_in[10];
    const float* bvo = (const float*)d_in[11];
    const float* Wqo = (const float*)d_in[12];
    const float* bqo = (const float*)d_in[13];
    float* out = (float*)d_out;                     // [v: 8388608][q: 4194304] f32

    char* w = (char*)d_ws;
    float* vmean = (float*)(w + 0);                 // 32 KB
    float* qmean = (float*)(w + 32768);
    float* gv4q  = (float*)(w + 65536);
    float* gq4v  = (float*)(w + 98304);
    u16* cWt  = (u16*)(w + (1 << 20));              // 6 MB (trans weight bf16)
    u16* cWo  = (u16*)(w + (1 << 20) + 6291456);    // 2 MB (proj weight bf16)
    u16* aReg = (u16*)(w + (16 << 20));             // 16 MB (relu acts / residual sum)
    u16* tReg = (u16*)(w + (32 << 20));             // 48 MB (trans)

    // stats + gates
    hipMemsetAsync(vmean, 0, 65536, stream);        // covers vmean + qmean
    mean_kernel<<<dim3(32, 8), 256, 0, stream>>>(v, vmean, 1024, 128);
    mean_kernel<<<dim3(32, 8), 256, 0, stream>>>(q, qmean, 512, 64);
    gate_kernel<<<2048, 256, 0, stream>>>(vmean, Wg_v4q, bg_v4q, gv4q);  // for q pipeline
    gate_kernel<<<2048, 256, 0, stream>>>(qmean, Wg_q4v, bg_q4v, gq4v);  // for v pipeline

    // ---- q phase ----
    u16* crq  = aReg;                               // bf16 relu(q), 8 MB
    u16* qt   = tReg;                               // [8,512,3072] bf16, 24 MB
    u16* qres = aReg;                               // bf16(q + attn), overwrites crq
    cvt_kernel<<<2048, 256, 0, stream>>>(q, crq, 524288, 1);
    cvt_kernel<<<1536, 256, 0, stream>>>(Wq, cWt, 393216, 0);
    cvt_kernel<<<512, 256, 0, stream>>>(Wqo, cWo, 131072, 0);
    gemm_bt_kernel<<<dim3(24, 32), 256, 0, stream>>>(crq, cWt, bq, gv4q, qt, nullptr,
                                                     4096, 3072, 1024, 512, 2048);
    attn_kernel<<<dim3(4, 64), 512, 0, stream>>>(qt, q, qres, 512);
    gemm_bt_kernel<<<dim3(8, 32), 256, 0, stream>>>(qres, cWo, bqo, nullptr, nullptr,
                                                    out + 8388608, 4096, 1024, 1024, 512, 0);

    // ---- v phase ----
    u16* crv  = aReg;                               // bf16 relu(v), 16 MB
    u16* vt   = tReg;                               // [8,1024,3072] bf16, 48 MB
    u16* vres = aReg;
    cvt_kernel<<<4096, 256, 0, stream>>>(v, crv, 1048576, 1);
    cvt_kernel<<<1536, 256, 0, stream>>>(Wv, cWt, 393216, 0);
    cvt_kernel<<<512, 256, 0, stream>>>(Wvo, cWo, 131072, 0);
    gemm_bt_kernel<<<dim3(24, 64), 256, 0, stream>>>(crv, cWt, bv, gq4v, vt, nullptr,
                                                     8192, 3072, 1024, 1024, 2048);
    attn_kernel<<<dim3(8, 64), 512, 0, stream>>>(vt, v, vres, 1024);
    gemm_bt_kernel<<<dim3(8, 64), 256, 0, stream>>>(vres, cWo, bvo, nullptr, nullptr,
                                                    out, 8192, 1024, 1024, 1024, 0);
}

// Round 8
// 538.354 us; speedup vs baseline: 1.2337x; 1.2337x over previous
//
#include <hip/hip_runtime.h>

typedef unsigned short u16;
typedef unsigned int u32;
typedef __attribute__((ext_vector_type(8))) short short8;
typedef __attribute__((ext_vector_type(4))) float floatx4;

__device__ __forceinline__ float bf2f(u16 x) {
    union { u32 u; float f; } c; c.u = ((u32)x) << 16; return c.f;
}
__device__ __forceinline__ u16 f2bf(float f) {
    union { float f; u32 u; } c; c.f = f;
    return (u16)((c.u + 0x7FFFu + ((c.u >> 16) & 1u)) >> 16);
}
// pack two f32 -> one u32 of 2x bf16 (RNE). Portable (no inline asm; per
// m240 the compiler schedules scalar casts better than hand-written cvt_pk).
__device__ __forceinline__ u32 pack_bf16(float lo, float hi) {
    return ((u32)f2bf(lo)) | (((u32)f2bf(hi)) << 16);
}

// async global->LDS, 16B per lane. LDS dest = wave-uniform base + lane*16.
#define GLD_LDS(g, l) __builtin_amdgcn_global_load_lds( \
    (const __attribute__((address_space(1))) u32*)(g),  \
    (__attribute__((address_space(3))) u32*)(l), 16, 0, 0)

// ---------------- f32 -> bf16 convert (optional fused relu) ----------------

__global__ void cvt_kernel(const float* __restrict__ src, u16* __restrict__ dst,
                           int n8, int do_relu) {
    int i = blockIdx.x * 256 + threadIdx.x;
    if (i >= n8) return;
    float4 a = ((const float4*)src)[2 * i];
    float4 b = ((const float4*)src)[2 * i + 1];
    float v[8] = {a.x, a.y, a.z, a.w, b.x, b.y, b.z, b.w};
    short8 o;
#pragma unroll
    for (int j = 0; j < 8; j++) {
        float x = v[j];
        if (do_relu) x = fmaxf(x, 0.f);
        o[j] = (short)f2bf(x);
    }
    ((short8*)dst)[i] = o;
}

// ---------------- stats / gates (pure f32) ----------------

// column mean over sequence: x [B,N,1024] f32 -> out [B*1024] f32 (pre-zeroed)
__global__ void mean_kernel(const float* __restrict__ x, float* __restrict__ out,
                            int N, int chunk) {
    int idx = blockIdx.x * 256 + threadIdx.x;   // (b,d) in [0, 8192)
    int b = idx >> 10, d = idx & 1023;
    int nlo = blockIdx.y * chunk;
    const float* p = x + (size_t)b * N * 1024 + (size_t)nlo * 1024 + d;
    float s = 0.f;
    for (int n = 0; n < chunk; n++) s += p[(size_t)n * 1024];
    atomicAdd(out + idx, s * (1.0f / (float)N));
}

// gate[b,n] = 1 + sigmoid( relu(mean[b,:]) . Wg[n,:] + bg[n] ), one wave/output
__global__ __launch_bounds__(256) void gate_kernel(const float* __restrict__ mean,
                                                   const float* __restrict__ Wg,
                                                   const float* __restrict__ bg,
                                                   float* __restrict__ gout) {
    int gw = blockIdx.x * 4 + (threadIdx.x >> 6);   // [0, 8192)
    int lane = threadIdx.x & 63;
    int b = gw >> 10, n = gw & 1023;
    const float* wr = Wg + (size_t)n * 1024;
    const float* mr = mean + b * 1024;
    float acc = 0.f;
    for (int k = lane; k < 1024; k += 64)
        acc += fmaxf(mr[k], 0.f) * wr[k];
#pragma unroll
    for (int m = 1; m < 64; m <<= 1) acc += __shfl_xor(acc, m, 64);
    if (lane == 0) {
        float xg = acc + bg[n];
        gout[gw] = 1.f + 1.f / (1.f + __expf(-xg));
    }
}

// ---------------- GEMM: C[M,N] = A[M,K] . W[N,K]^T + bias, optional (1+gate) ----------------
// A, W bf16 (pre-converted in ws). 128x128 tile, BK=32, 4 waves (2x2), each
// wave 4x4 MFMA 16x16x32. DOUBLE-BUFFERED GLD_LDS staging (T3 2-phase).
// XCD-aware bijective block swizzle (all grids nwg % 8 == 0).
// Output bf16 (Ch) or f32 (Cf), exactly one non-null.

__global__ __launch_bounds__(256) void gemm_bt_kernel(
    const u16* __restrict__ A, const u16* __restrict__ W,
    const float* __restrict__ bias, const float* __restrict__ gate,
    u16* __restrict__ Ch, float* __restrict__ Cf,
    int M, int N, int K, int seq, int gateN)
{
    __shared__ u16 As[2][128 * 32];   // [m][k] row-major, 2 x 8 KB
    __shared__ u16 Bs[2][128 * 32];   // [n][k] row-major, 2 x 8 KB

    const int tid = threadIdx.x;
    const int wave = tid >> 6, lane = tid & 63, quad = lane >> 4, l15 = lane & 15;

    // XCD swizzle: contiguous grid chunk per XCD (bijective since nwg%8==0)
    const u32 gx = gridDim.x;
    const u32 flat = blockIdx.y * gx + blockIdx.x;
    const u32 per = (gx * gridDim.y) >> 3;
    const u32 swz = (flat & 7) * per + (flat >> 3);
    const int m0 = (int)(swz / gx) * 128, n0 = (int)(swz % gx) * 128;

    const int wm = (wave >> 1) * 64, wn = (wave & 1) * 64;

    floatx4 acc[4][4] = {};

    // staging map: round r covers tile bytes [r*4096 + wave*1024 + lane*16, +16)
    const int e0 = (wave * 1024 + lane * 16) >> 1;       // elements, round 0
    const int sr0 = e0 >> 5, sc0 = e0 & 31;
    const int e1 = e0 + 2048;                            // round 1
    const int sr1 = e1 >> 5, sc1 = e1 & 31;
    const size_t aoff0 = (size_t)(m0 + sr0) * K + sc0;
    const size_t aoff1 = (size_t)(m0 + sr1) * K + sc1;
    const size_t boff0 = (size_t)(n0 + sr0) * K + sc0;
    const size_t boff1 = (size_t)(n0 + sr1) * K + sc1;

    // prologue: stage K-tile 0 into buffer 0
    GLD_LDS(A + aoff0, As[0] + wave * 512);
    GLD_LDS(A + aoff1, As[0] + 2048 + wave * 512);
    GLD_LDS(W + boff0, Bs[0] + wave * 512);
    GLD_LDS(W + boff1, Bs[0] + 2048 + wave * 512);
    __syncthreads();

    int cur = 0;
    for (int k0 = 0; k0 < K; k0 += 32) {
        const int nxt = cur ^ 1;
        // issue next tile's DMA early (hides under this tile's compute)
        if (k0 + 32 < K) {
            GLD_LDS(A + aoff0 + k0 + 32, As[nxt] + wave * 512);
            GLD_LDS(A + aoff1 + k0 + 32, As[nxt] + 2048 + wave * 512);
            GLD_LDS(W + boff0 + k0 + 32, Bs[nxt] + wave * 512);
            GLD_LDS(W + boff1 + k0 + 32, Bs[nxt] + 2048 + wave * 512);
        }

        short8 af[4], bfr[4];
#pragma unroll
        for (int i = 0; i < 4; i++) {
            af[i]  = *(const short8*)(As[cur] + (wm + i * 16 + l15) * 32 + quad * 8);
            bfr[i] = *(const short8*)(Bs[cur] + (wn + i * 16 + l15) * 32 + quad * 8);
        }
#pragma unroll
        for (int mi = 0; mi < 4; mi++)
#pragma unroll
            for (int ni = 0; ni < 4; ni++)
                acc[mi][ni] = __builtin_amdgcn_mfma_f32_16x16x32_bf16(af[mi], bfr[ni], acc[mi][ni], 0, 0, 0);
        __syncthreads();
        cur = nxt;
    }

    const int b = m0 / seq;
#pragma unroll
    for (int ni = 0; ni < 4; ni++) {
        const int ncol = n0 + wn + ni * 16 + l15;
        const float bsv = bias[ncol];
        float g = 1.f;
        if (gate != nullptr && ncol < gateN) g = gate[b * 1024 + (ncol & 1023)];
#pragma unroll
        for (int mi = 0; mi < 4; mi++) {
            const int row = m0 + wm + mi * 16 + quad * 4;
#pragma unroll
            for (int r = 0; r < 4; r++) {
                float val = (acc[mi][ni][r] + bsv) * g;
                size_t idx = (size_t)(row + r) * N + ncol;
                if (Cf) Cf[idx] = val; else Ch[idx] = f2bf(val);
            }
        }
    }
}

// ---------------- fused flash attention (+ fused residual epilogue) ----------------
// T: [B, N, 3072] bf16 gated trans (k | q | v thirds, 8 heads x 128 each).
// X: [B, N, 1024] f32 original input for the residual.
// U: [B, N, 1024] bf16 out = bf16(X + attn).
// Block = (128 q-rows, b*8+h), 512 threads / 8 waves, ONE 16-row group per
// wave. __launch_bounds__(512, 2): r7's (512,4) was interpreted as CUDA-style
// min-BLOCKS-per-CU (4 blk x 8 waves / 4 SIMD = 8 waves/SIMD -> VGPR capped
// at 64 -> massive scratch spills: WRITE_SIZE 16->59 MB, FETCH 155->336 MB,
// attn 98->169 us). Arg=2 caps at 128 under blocks-semantics (2 blk/CU,
// 4 waves/SIMD — the intended occupancy) and is unconstraining under
// waves-semantics; state fits ~110 VGPR either way.
// KVBLK=64, double-buffered K/V (T3) + issue-early/write-late V (T14).
// SWAPPED QK^T (T12): mfma(K,Q) puts P row-local to lane (q=l15); softmax
// row-reduce = in-reg tree + 2 shuffles; defer-max (T13, THR=8).
// Packed-P scratch lives in the wave's PRIVATE 2KB slice of Vs[nxt]
// (rows [16w,16w+16)): pack -> pf read -> PV(Vs[cur]) -> late V write
// overwrites the dead P. Race-free: region is wave-private, in-order per
// wave, PV reads only Vs[cur]. P words XOR-swizzled ^((l15&7)<<2).
// XCD swizzle: all qb-blocks of one (b,h) on one XCD's L2.

__global__ __launch_bounds__(512, 2) void attn_kernel(
    const u16* __restrict__ T, const float* __restrict__ X,
    u16* __restrict__ U, int N)
{
    __shared__ __align__(16) u16 Ks[2][64 * 128];  // 2 x 16 KB, swizzled [kv][d]
    __shared__ __align__(16) u16 Vs[2][128 * 64];  // 2 x 16 KB, swizzled [d][kv]

    const int tid = threadIdx.x;
    const int wave = tid >> 6, lane = tid & 63, quad = (lane >> 4) & 3, l15 = lane & 15;

    // XCD swizzle: assume flat-id round-robin over 8 XCDs; give each XCD
    // whole (b,h) groups so K/V stay in one L2. Bijective for gridY=64.
    const int f = blockIdx.y * gridDim.x + blockIdx.x;
    const int i3 = f >> 3;
    const int qb = i3 % gridDim.x;
    const int bh = (f & 7) * 8 + i3 / gridDim.x;
    const int b = bh >> 3, h = bh & 7;

    const size_t base = (size_t)b * N * 3072;
    const int kcol = h * 128, qcol = 1024 + h * 128, vcol = 2048 + h * 128;

    // Q fragments: this wave's 16 rows, row = qrow0 + l15
    short8 qf[4];
    const int qrow0 = qb * 128 + wave * 16;
#pragma unroll
    for (int c = 0; c < 4; c++)
        qf[c] = *(const short8*)(T + base + (size_t)(qrow0 + l15) * 3072
                                   + qcol + c * 32 + quad * 8);

    floatx4 o[8] = {};
    float mrow = -1e30f, lrow = 0.f;
    const float scale = 0.08838834764831845f;  // 1/sqrt(128)

    // K staging map: 2 rounds x (512 lanes x 16B) = 16 KB.
    // LDS byte ob holds K[kv = ob>>8][d = (((ob>>4)&15) ^ (kv&15))*8 .. +8)
    int kst_kv[2], kst_d[2];
#pragma unroll
    for (int r = 0; r < 2; r++) {
        int ob = r * 8192 + wave * 1024 + lane * 16;
        int kv = ob >> 8;
        kst_kv[r] = kv;
        kst_d[r] = ((((ob >> 4) & 15) ^ (kv & 15)) << 3);
    }
    // V staging: thread covers rows (vkv, vkv+1) x d-slice vd8*8..+7;
    // wave w writes exactly Vs rows [16w, 16w+16) = its private 2KB slice.
    const int vkv = (tid & 31) * 2;
    const int vd8 = tid >> 5;            // [0,16)

    // ---- prologue: stage tile 0 ----
    short8 v0, v1;
#pragma unroll
    for (int r = 0; r < 2; r++)
        GLD_LDS(T + base + (size_t)kst_kv[r] * 3072 + kcol + kst_d[r],
                Ks[0] + r * 4096 + wave * 512);
    {
        const u16* vp = T + base + (size_t)vkv * 3072 + vcol + vd8 * 8;
        v0 = *(const short8*)vp;
        v1 = *(const short8*)(vp + 3072);
    }
#pragma unroll
    for (int j = 0; j < 8; j++) {
        u32 wv = ((u32)(u16)v0[j]) | (((u32)(u16)v1[j]) << 16);
        *(u32*)((char*)Vs[0] + (size_t)(vd8 * 8 + j) * 128
                + ((((vkv >> 3) ^ j)) << 4) + ((vkv * 2) & 15)) = wv;
    }
    __syncthreads();

    int cur = 0;
    for (int kt = 0; kt < N; kt += 64) {
        const int nxt = cur ^ 1;
        const bool more = (kt + 64) < N;

        // ---- issue next tile's staging EARLY (hides under compute) ----
        if (more) {
#pragma unroll
            for (int r = 0; r < 2; r++)
                GLD_LDS(T + base + (size_t)(kt + 64 + kst_kv[r]) * 3072 + kcol + kst_d[r],
                        Ks[nxt] + r * 4096 + wave * 512);
            const u16* vp = T + base + (size_t)(kt + 64 + vkv) * 3072 + vcol + vd8 * 8;
            v0 = *(const short8*)vp;
            v1 = *(const short8*)(vp + 3072);
        }

        // ---- QK^T (swapped): p[ni][r] = P[q=l15][kv=ni*16+quad*4+r] ----
        float p[4][4];
        __builtin_amdgcn_s_setprio(1);
#pragma unroll
        for (int ni = 0; ni < 4; ni++) {
            short8 kf[4];
#pragma unroll
            for (int c = 0; c < 4; c++)
                kf[c] = *(const short8*)(Ks[cur] + (ni * 16 + l15) * 128
                                            + (((c * 4 + quad) ^ l15) << 3));
            floatx4 s = {0.f, 0.f, 0.f, 0.f};
#pragma unroll
            for (int c = 0; c < 4; c++)
                s = __builtin_amdgcn_mfma_f32_16x16x32_bf16(kf[c], qf[c], s, 0, 0, 0);
#pragma unroll
            for (int r = 0; r < 4; r++) p[ni][r] = s[r] * scale;
        }
        __builtin_amdgcn_s_setprio(0);

        // ---- online softmax, lane-local rows (q=l15), defer-max THR=8 ----
        {
            float tm = p[0][0];
#pragma unroll
            for (int ni = 0; ni < 4; ni++)
#pragma unroll
                for (int r = 0; r < 4; r++) tm = fmaxf(tm, p[ni][r]);
            tm = fmaxf(tm, __shfl_xor(tm, 16, 64));
            tm = fmaxf(tm, __shfl_xor(tm, 32, 64));
            const bool need = __any(tm > mrow + 8.f);   // wave-uniform
            if (need) {
                float mnew = fmaxf(mrow, tm);
                float alpha = __expf(mrow - mnew);
                mrow = mnew;
                float ps = 0.f;
#pragma unroll
                for (int ni = 0; ni < 4; ni++)
#pragma unroll
                    for (int r = 0; r < 4; r++) {
                        float pe = __expf(p[ni][r] - mnew);
                        p[ni][r] = pe;
                        ps += pe;
                    }
                ps += __shfl_xor(ps, 16, 64);
                ps += __shfl_xor(ps, 32, 64);
                lrow = lrow * alpha + ps;
#pragma unroll
                for (int r = 0; r < 4; r++) {
                    float ab = __shfl(alpha, quad * 4 + r, 64);
#pragma unroll
                    for (int nt = 0; nt < 8; nt++) o[nt][r] *= ab;
                }
            } else {
                float ps = 0.f;
#pragma unroll
                for (int ni = 0; ni < 4; ni++)
#pragma unroll
                    for (int r = 0; r < 4; r++) {
                        float pe = __expf(p[ni][r] - mrow);
                        p[ni][r] = pe;
                        ps += pe;
                    }
                ps += __shfl_xor(ps, 16, 64);
                ps += __shfl_xor(ps, 32, 64);
                lrow += ps;
            }
        }

        // ---- P pack into wave-private scratch (Vs[nxt] rows [16w,16w+16)) ----
        u32* pw = (u32*)((char*)Vs[nxt] + wave * 2048);
        const int xs = (l15 & 7) << 2;
#pragma unroll
        for (int ni = 0; ni < 4; ni++)
#pragma unroll
            for (int s2 = 0; s2 < 2; s2++)
                pw[l15 * 32 + ((ni * 8 + quad * 2 + s2) ^ xs)]
                    = pack_bf16(p[ni][2 * s2], p[ni][2 * s2 + 1]);
        short8 pf[2];
#pragma unroll
        for (int kc = 0; kc < 2; kc++)
            pf[kc] = *(const short8*)(pw + l15 * 32 + ((kc * 16 + quad * 4) ^ xs));

        // ---- PV: 16 MFMA, swizzled conflict-free V reads ----
        __builtin_amdgcn_s_setprio(1);
#pragma unroll
        for (int nt = 0; nt < 8; nt++) {
#pragma unroll
            for (int kc = 0; kc < 2; kc++) {
                short8 vf = *(const short8*)(Vs[cur] + (nt * 16 + l15) * 64
                                + (((kc * 4 + quad) ^ (l15 & 7)) << 3));
                o[nt] = __builtin_amdgcn_mfma_f32_16x16x32_bf16(pf[kc], vf, o[nt], 0, 0, 0);
            }
        }
        __builtin_amdgcn_s_setprio(0);

        // ---- late V write into own slice of Vs[nxt] (overwrites dead P) ----
        if (more) {
#pragma unroll
            for (int j = 0; j < 8; j++) {
                u32 wv = ((u32)(u16)v0[j]) | (((u32)(u16)v1[j]) << 16);
                *(u32*)((char*)Vs[nxt] + (size_t)(vd8 * 8 + j) * 128
                        + ((((vkv >> 3) ^ j)) << 4) + ((vkv * 2) & 15)) = wv;
            }
        }
        __syncthreads();
        cur = nxt;
    }

    // ---- epilogue: broadcast l, fuse residual: U = bf16(X + O/l) ----
    const size_t ub = (size_t)b * N * 1024;
#pragma unroll
    for (int r = 0; r < 4; r++) {
        float lb = __shfl(lrow, quad * 4 + r, 64);
        float inv = 1.f / lb;
        const size_t row = qb * 128 + wave * 16 + quad * 4 + r;
#pragma unroll
        for (int nt = 0; nt < 8; nt++) {
            const size_t idx = ub + row * 1024 + h * 128 + nt * 16 + l15;
            U[idx] = f2bf(X[idx] + o[nt][r] * inv);
        }
    }
}

// ---------------- launch ----------------
// Inputs f32, outputs f32 (both per reference dtypes). ws peak = 80.1 MB:
// stats 128 KB | weights 8 MB @1MB | activations 16 MB @16MB | trans 48 MB @32MB.
// q phase then v phase reuse the same regions sequentially. Residual add is
// fused into attn's epilogue (writes bf16(X + attn) into aReg, consumed by
// the output-proj GEMM).

extern "C" void kernel_launch(void* const* d_in, const int* in_sizes, int n_in,
                              void* d_out, int out_size, void* d_ws, size_t ws_size,
                              hipStream_t stream) {
    (void)in_sizes; (void)n_in; (void)out_size; (void)ws_size;
    const float* v   = (const float*)d_in[0];
    const float* q   = (const float*)d_in[1];
    const float* Wg_v4q = (const float*)d_in[2];
    const float* bg_v4q = (const float*)d_in[3];
    const float* Wg_q4v = (const float*)d_in[4];
    const float* bg_q4v = (const float*)d_in[5];
    const float* Wv  = (const float*)d_in[6];
    const float* bv  = (const float*)d_in[7];
    const float* Wq  = (const float*)d_in[8];
    const float* bq  = (const float*)d_in[9];
    const float* Wvo = (const float*)d_in[10];
    const float* bvo = (const float*)d_in[11];
    const float* Wqo = (const float*)d_in[12];
    const float* bqo = (const float*)d_in[13];
    float* out = (float*)d_out;                     // [v: 8388608][q: 4194304] f32

    char* w = (char*)d_ws;
    float* vmean = (float*)(w + 0);                 // 32 KB
    float* qmean = (float*)(w + 32768);
    float* gv4q  = (float*)(w + 65536);
    float* gq4v  = (float*)(w + 98304);
    u16* cWt  = (u16*)(w + (1 << 20));              // 6 MB (trans weight bf16)
    u16* cWo  = (u16*)(w + (1 << 20) + 6291456);    // 2 MB (proj weight bf16)
    u16* aReg = (u16*)(w + (16 << 20));             // 16 MB (relu acts / residual sum)
    u16* tReg = (u16*)(w + (32 << 20));             // 48 MB (trans)

    // stats + gates
    hipMemsetAsync(vmean, 0, 65536, stream);        // covers vmean + qmean
    mean_kernel<<<dim3(32, 8), 256, 0, stream>>>(v, vmean, 1024, 128);
    mean_kernel<<<dim3(32, 8), 256, 0, stream>>>(q, qmean, 512, 64);
    gate_kernel<<<2048, 256, 0, stream>>>(vmean, Wg_v4q, bg_v4q, gv4q);  // for q pipeline
    gate_kernel<<<2048, 256, 0, stream>>>(qmean, Wg_q4v, bg_q4v, gq4v);  // for v pipeline

    // ---- q phase ----
    u16* crq  = aReg;                               // bf16 relu(q), 8 MB
    u16* qt   = tReg;                               // [8,512,3072] bf16, 24 MB
    u16* qres = aReg;                               // bf16(q + attn), overwrites crq
    cvt_kernel<<<2048, 256, 0, stream>>>(q, crq, 524288, 1);
    cvt_kernel<<<1536, 256, 0, stream>>>(Wq, cWt, 393216, 0);
    cvt_kernel<<<512, 256, 0, stream>>>(Wqo, cWo, 131072, 0);
    gemm_bt_kernel<<<dim3(24, 32), 256, 0, stream>>>(crq, cWt, bq, gv4q, qt, nullptr,
                                                     4096, 3072, 1024, 512, 2048);
    attn_kernel<<<dim3(4, 64), 512, 0, stream>>>(qt, q, qres, 512);
    gemm_bt_kernel<<<dim3(8, 32), 256, 0, stream>>>(qres, cWo, bqo, nullptr, nullptr,
                                                    out + 8388608, 4096, 1024, 1024, 512, 0);

    // ---- v phase ----
    u16* crv  = aReg;                               // bf16 relu(v), 16 MB
    u16* vt   = tReg;                               // [8,1024,3072] bf16, 48 MB
    u16* vres = aReg;
    cvt_kernel<<<4096, 256, 0, stream>>>(v, crv, 1048576, 1);
    cvt_kernel<<<1536, 256, 0, stream>>>(Wv, cWt, 393216, 0);
    cvt_kernel<<<512, 256, 0, stream>>>(Wvo, cWo, 131072, 0);
    gemm_bt_kernel<<<dim3(24, 64), 256, 0, stream>>>(crv, cWt, bv, gq4v, vt, nullptr,
                                                     8192, 3072, 1024, 1024, 2048);
    attn_kernel<<<dim3(8, 64), 512, 0, stream>>>(vt, v, vres, 1024);
    gemm_bt_kernel<<<dim3(8, 64), 256, 0, stream>>>(vres, cWo, bvo, nullptr, nullptr,
                                                    out, 8192, 1024, 1024, 1024, 0);
}

// Round 10
// 459.246 us; speedup vs baseline: 1.4463x; 1.1723x over previous
//
#include <hip/hip_runtime.h>

typedef unsigned short u16;
typedef unsigned int u32;
typedef __attribute__((ext_vector_type(8))) short short8;
typedef __attribute__((ext_vector_type(4))) float floatx4;

__device__ __forceinline__ float bf2f(u16 x) {
    union { u32 u; float f; } c; c.u = ((u32)x) << 16; return c.f;
}
__device__ __forceinline__ u16 f2bf(float f) {
    union { float f; u32 u; } c; c.f = f;
    return (u16)((c.u + 0x7FFFu + ((c.u >> 16) & 1u)) >> 16);
}
// pack two f32 -> one u32 of 2x bf16 (RNE)
__device__ __forceinline__ u32 pack_bf16(float lo, float hi) {
    return ((u32)f2bf(lo)) | (((u32)f2bf(hi)) << 16);
}

// async global->LDS, 16B per lane. LDS dest = wave-uniform base + lane*16.
#define GLD_LDS(g, l) __builtin_amdgcn_global_load_lds( \
    (const __attribute__((address_space(1))) u32*)(g),  \
    (__attribute__((address_space(3))) u32*)(l), 16, 0, 0)

// ---------------- fused mean + relu-cvt (v and q in one launch) ----------------
// grid (64, 8) x 256. idx<8192: v (N=1024, chunks of 128); else q (N=512,
// chunks of 64). Each thread: one (b,d) column within chunk y — accumulates
// raw f32 partial sum AND writes bf16(relu(x)). Partials -> pmean[j][16384].

__global__ __launch_bounds__(256) void meancvt_kernel(
    const float* __restrict__ v, const float* __restrict__ q,
    u16* __restrict__ crv, u16* __restrict__ crq, float* __restrict__ pmean)
{
    const int idx = blockIdx.x * 256 + threadIdx.x;   // [0, 16384)
    const int j = blockIdx.y;                          // chunk [0,8)
    const int half = idx >> 13;                        // 0 = v, 1 = q
    const int lidx = idx & 8191;
    const int b = lidx >> 10, d = lidx & 1023;
    float s = 0.f;
    if (half == 0) {
        const float* p = v + (size_t)b * 1024 * 1024 + (size_t)(j * 128) * 1024 + d;
        u16* cw = crv + (size_t)b * 1024 * 1024 + (size_t)(j * 128) * 1024 + d;
        for (int n = 0; n < 128; n++) {
            float x = p[(size_t)n * 1024];
            cw[(size_t)n * 1024] = f2bf(fmaxf(x, 0.f));
            s += x;
        }
    } else {
        const float* p = q + (size_t)b * 512 * 1024 + (size_t)(j * 64) * 1024 + d;
        u16* cw = crq + (size_t)b * 512 * 1024 + (size_t)(j * 64) * 1024 + d;
        for (int n = 0; n < 64; n++) {
            float x = p[(size_t)n * 1024];
            cw[(size_t)n * 1024] = f2bf(fmaxf(x, 0.f));
            s += x;
        }
    }
    pmean[j * 16384 + idx] = s;
}

// ---------------- gates (both sets, one launch) ----------------

__global__ __launch_bounds__(256) void gate_kernel(
    const float* __restrict__ pmean,
    const float* __restrict__ Wg0, const float* __restrict__ bg0, float* __restrict__ g0,
    const float* __restrict__ Wg1, const float* __restrict__ bg1, float* __restrict__ g1)
{
    int gw = blockIdx.x * 4 + (threadIdx.x >> 6);   // [0, 16384)
    int lane = threadIdx.x & 63;
    const int half = gw >> 13;
    const int lw = gw & 8191;
    const int b = lw >> 10, n = lw & 1023;
    const float* wr = (half ? Wg1 : Wg0) + (size_t)n * 1024;
    const float invN = half ? (1.f / 512.f) : (1.f / 1024.f);
    const int pbase = half * 8192 + b * 1024;
    float acc = 0.f;
    for (int k = lane; k < 1024; k += 64) {
        float m = 0.f;
#pragma unroll
        for (int j = 0; j < 8; j++) m += pmean[j * 16384 + pbase + k];
        acc += fmaxf(m * invN, 0.f) * wr[k];
    }
#pragma unroll
    for (int msk = 1; msk < 64; msk <<= 1) acc += __shfl_xor(acc, msk, 64);
    if (lane == 0) {
        float xg = acc + (half ? bg1 : bg0)[n];
        (half ? g1 : g0)[lw] = 1.f + 1.f / (1.f + __expf(-xg));
    }
}

// ---------------- weight cvt: trans W (3072x1024) + proj Wo (1024x1024) ----------------

__global__ void wcvt_kernel(const float* __restrict__ Wt, const float* __restrict__ Wo,
                            u16* __restrict__ cWt, u16* __restrict__ cWo) {
    int i = blockIdx.x * 256 + threadIdx.x;           // [0, 524288)
    const float* src; u16* dst; int ii;
    if (i < 393216) { src = Wt; dst = cWt; ii = i; }
    else            { src = Wo; dst = cWo; ii = i - 393216; }
    float4 a = ((const float4*)src)[2 * ii];
    float4 b = ((const float4*)src)[2 * ii + 1];
    float vv[8] = {a.x, a.y, a.z, a.w, b.x, b.y, b.z, b.w};
    short8 o;
#pragma unroll
    for (int j = 0; j < 8; j++) o[j] = (short)f2bf(vv[j]);
    ((short8*)dst)[ii] = o;
}

// ---------------- GEMM: C[M,N] = A[M,K] . W[N,K]^T + bias, optional (1+gate) ----------------
// (unchanged from r8) 128x128 tile, BK=32, 4 waves, double-buffered GLD_LDS
// (T3 2-phase), XCD-aware bijective swizzle. Output bf16 (Ch) or f32 (Cf).

__global__ __launch_bounds__(256) void gemm_bt_kernel(
    const u16* __restrict__ A, const u16* __restrict__ W,
    const float* __restrict__ bias, const float* __restrict__ gate,
    u16* __restrict__ Ch, float* __restrict__ Cf,
    int M, int N, int K, int seq, int gateN)
{
    __shared__ u16 As[2][128 * 32];   // [m][k] row-major, 2 x 8 KB
    __shared__ u16 Bs[2][128 * 32];   // [n][k] row-major, 2 x 8 KB

    const int tid = threadIdx.x;
    const int wave = tid >> 6, lane = tid & 63, quad = lane >> 4, l15 = lane & 15;

    // XCD swizzle: contiguous grid chunk per XCD (bijective since nwg%8==0)
    const u32 gx = gridDim.x;
    const u32 flat = blockIdx.y * gx + blockIdx.x;
    const u32 per = (gx * gridDim.y) >> 3;
    const u32 swz = (flat & 7) * per + (flat >> 3);
    const int m0 = (int)(swz / gx) * 128, n0 = (int)(swz % gx) * 128;

    const int wm = (wave >> 1) * 64, wn = (wave & 1) * 64;

    floatx4 acc[4][4] = {};

    // staging map: round r covers tile bytes [r*4096 + wave*1024 + lane*16, +16)
    const int e0 = (wave * 1024 + lane * 16) >> 1;       // elements, round 0
    const int sr0 = e0 >> 5, sc0 = e0 & 31;
    const int e1 = e0 + 2048;                            // round 1
    const int sr1 = e1 >> 5, sc1 = e1 & 31;
    const size_t aoff0 = (size_t)(m0 + sr0) * K + sc0;
    const size_t aoff1 = (size_t)(m0 + sr1) * K + sc1;
    const size_t boff0 = (size_t)(n0 + sr0) * K + sc0;
    const size_t boff1 = (size_t)(n0 + sr1) * K + sc1;

    // prologue: stage K-tile 0 into buffer 0
    GLD_LDS(A + aoff0, As[0] + wave * 512);
    GLD_LDS(A + aoff1, As[0] + 2048 + wave * 512);
    GLD_LDS(W + boff0, Bs[0] + wave * 512);
    GLD_LDS(W + boff1, Bs[0] + 2048 + wave * 512);
    __syncthreads();

    int cur = 0;
    for (int k0 = 0; k0 < K; k0 += 32) {
        const int nxt = cur ^ 1;
        if (k0 + 32 < K) {
            GLD_LDS(A + aoff0 + k0 + 32, As[nxt] + wave * 512);
            GLD_LDS(A + aoff1 + k0 + 32, As[nxt] + 2048 + wave * 512);
            GLD_LDS(W + boff0 + k0 + 32, Bs[nxt] + wave * 512);
            GLD_LDS(W + boff1 + k0 + 32, Bs[nxt] + 2048 + wave * 512);
        }

        short8 af[4], bfr[4];
#pragma unroll
        for (int i = 0; i < 4; i++) {
            af[i]  = *(const short8*)(As[cur] + (wm + i * 16 + l15) * 32 + quad * 8);
            bfr[i] = *(const short8*)(Bs[cur] + (wn + i * 16 + l15) * 32 + quad * 8);
        }
#pragma unroll
        for (int mi = 0; mi < 4; mi++)
#pragma unroll
            for (int ni = 0; ni < 4; ni++)
                acc[mi][ni] = __builtin_amdgcn_mfma_f32_16x16x32_bf16(af[mi], bfr[ni], acc[mi][ni], 0, 0, 0);
        __syncthreads();
        cur = nxt;
    }

    const int b = m0 / seq;
#pragma unroll
    for (int ni = 0; ni < 4; ni++) {
        const int ncol = n0 + wn + ni * 16 + l15;
        const float bsv = bias[ncol];
        float g = 1.f;
        if (gate != nullptr && ncol < gateN) g = gate[b * 1024 + (ncol & 1023)];
#pragma unroll
        for (int mi = 0; mi < 4; mi++) {
            const int row = m0 + wm + mi * 16 + quad * 4;
#pragma unroll
            for (int r = 0; r < 4; r++) {
                float val = (acc[mi][ni][r] + bsv) * g;
                size_t idx = (size_t)(row + r) * N + ncol;
                if (Cf) Cf[idx] = val; else Ch[idx] = f2bf(val);
            }
        }
    }
}

// ---------------- fused flash attention (+ fused residual epilogue) ----------------
// (unchanged from r8) 512 thr / 8 waves / 16 rows per wave, launch_bounds(512,2),
// KVBLK=64 dbuf (T3/T14), swapped QK^T (T12), defer-max (T13), P-scratch in
// Vs[nxt] wave-private slice, XCD swizzle.

__global__ __launch_bounds__(512, 2) void attn_kernel(
    const u16* __restrict__ T, const float* __restrict__ X,
    u16* __restrict__ U, int N)
{
    __shared__ __align__(16) u16 Ks[2][64 * 128];  // 2 x 16 KB, swizzled [kv][d]
    __shared__ __align__(16) u16 Vs[2][128 * 64];  // 2 x 16 KB, swizzled [d][kv]

    const int tid = threadIdx.x;
    const int wave = tid >> 6, lane = tid & 63, quad = (lane >> 4) & 3, l15 = lane & 15;

    const int f = blockIdx.y * gridDim.x + blockIdx.x;
    const int i3 = f >> 3;
    const int qb = i3 % gridDim.x;
    const int bh = (f & 7) * 8 + i3 / gridDim.x;
    const int b = bh >> 3, h = bh & 7;

    const size_t base = (size_t)b * N * 3072;
    const int kcol = h * 128, qcol = 1024 + h * 128, vcol = 2048 + h * 128;

    short8 qf[4];
    const int qrow0 = qb * 128 + wave * 16;
#pragma unroll
    for (int c = 0; c < 4; c++)
        qf[c] = *(const short8*)(T + base + (size_t)(qrow0 + l15) * 3072
                                   + qcol + c * 32 + quad * 8);

    floatx4 o[8] = {};
    float mrow = -1e30f, lrow = 0.f;
    const float scale = 0.08838834764831845f;  // 1/sqrt(128)

    int kst_kv[2], kst_d[2];
#pragma unroll
    for (int r = 0; r < 2; r++) {
        int ob = r * 8192 + wave * 1024 + lane * 16;
        int kv = ob >> 8;
        kst_kv[r] = kv;
        kst_d[r] = ((((ob >> 4) & 15) ^ (kv & 15)) << 3);
    }
    const int vkv = (tid & 31) * 2;
    const int vd8 = tid >> 5;            // [0,16)

    short8 v0, v1;
#pragma unroll
    for (int r = 0; r < 2; r++)
        GLD_LDS(T + base + (size_t)kst_kv[r] * 3072 + kcol + kst_d[r],
                Ks[0] + r * 4096 + wave * 512);
    {
        const u16* vp = T + base + (size_t)vkv * 3072 + vcol + vd8 * 8;
        v0 = *(const short8*)vp;
        v1 = *(const short8*)(vp + 3072);
    }
#pragma unroll
    for (int j = 0; j < 8; j++) {
        u32 wv = ((u32)(u16)v0[j]) | (((u32)(u16)v1[j]) << 16);
        *(u32*)((char*)Vs[0] + (size_t)(vd8 * 8 + j) * 128
                + ((((vkv >> 3) ^ j)) << 4) + ((vkv * 2) & 15)) = wv;
    }
    __syncthreads();

    int cur = 0;
    for (int kt = 0; kt < N; kt += 64) {
        const int nxt = cur ^ 1;
        const bool more = (kt + 64) < N;

        if (more) {
#pragma unroll
            for (int r = 0; r < 2; r++)
                GLD_LDS(T + base + (size_t)(kt + 64 + kst_kv[r]) * 3072 + kcol + kst_d[r],
                        Ks[nxt] + r * 4096 + wave * 512);
            const u16* vp = T + base + (size_t)(kt + 64 + vkv) * 3072 + vcol + vd8 * 8;
            v0 = *(const short8*)vp;
            v1 = *(const short8*)(vp + 3072);
        }

        float p[4][4];
        __builtin_amdgcn_s_setprio(1);
#pragma unroll
        for (int ni = 0; ni < 4; ni++) {
            short8 kf[4];
#pragma unroll
            for (int c = 0; c < 4; c++)
                kf[c] = *(const short8*)(Ks[cur] + (ni * 16 + l15) * 128
                                            + (((c * 4 + quad) ^ l15) << 3));
            floatx4 s = {0.f, 0.f, 0.f, 0.f};
#pragma unroll
            for (int c = 0; c < 4; c++)
                s = __builtin_amdgcn_mfma_f32_16x16x32_bf16(kf[c], qf[c], s, 0, 0, 0);
#pragma unroll
            for (int r = 0; r < 4; r++) p[ni][r] = s[r] * scale;
        }
        __builtin_amdgcn_s_setprio(0);

        {
            float tm = p[0][0];
#pragma unroll
            for (int ni = 0; ni < 4; ni++)
#pragma unroll
                for (int r = 0; r < 4; r++) tm = fmaxf(tm, p[ni][r]);
            tm = fmaxf(tm, __shfl_xor(tm, 16, 64));
            tm = fmaxf(tm, __shfl_xor(tm, 32, 64));
            const bool need = __any(tm > mrow + 8.f);   // wave-uniform
            if (need) {
                float mnew = fmaxf(mrow, tm);
                float alpha = __expf(mrow - mnew);
                mrow = mnew;
                float ps = 0.f;
#pragma unroll
                for (int ni = 0; ni < 4; ni++)
#pragma unroll
                    for (int r = 0; r < 4; r++) {
                        float pe = __expf(p[ni][r] - mnew);
                        p[ni][r] = pe;
                        ps += pe;
                    }
                ps += __shfl_xor(ps, 16, 64);
                ps += __shfl_xor(ps, 32, 64);
                lrow = lrow * alpha + ps;
#pragma unroll
                for (int r = 0; r < 4; r++) {
                    float ab = __shfl(alpha, quad * 4 + r, 64);
#pragma unroll
                    for (int nt = 0; nt < 8; nt++) o[nt][r] *= ab;
                }
            } else {
                float ps = 0.f;
#pragma unroll
                for (int ni = 0; ni < 4; ni++)
#pragma unroll
                    for (int r = 0; r < 4; r++) {
                        float pe = __expf(p[ni][r] - mrow);
                        p[ni][r] = pe;
                        ps += pe;
                    }
                ps += __shfl_xor(ps, 16, 64);
                ps += __shfl_xor(ps, 32, 64);
                lrow += ps;
            }
        }

        u32* pw = (u32*)((char*)Vs[nxt] + wave * 2048);
        const int xs = (l15 & 7) << 2;
#pragma unroll
        for (int ni = 0; ni < 4; ni++)
#pragma unroll
            for (int s2 = 0; s2 < 2; s2++)
                pw[l15 * 32 + ((ni * 8 + quad * 2 + s2) ^ xs)]
                    = pack_bf16(p[ni][2 * s2], p[ni][2 * s2 + 1]);
        short8 pf[2];
#pragma unroll
        for (int kc = 0; kc < 2; kc++)
            pf[kc] = *(const short8*)(pw + l15 * 32 + ((kc * 16 + quad * 4) ^ xs));

        __builtin_amdgcn_s_setprio(1);
#pragma unroll
        for (int nt = 0; nt < 8; nt++) {
#pragma unroll
            for (int kc = 0; kc < 2; kc++) {
                short8 vf = *(const short8*)(Vs[cur] + (nt * 16 + l15) * 64
                                + (((kc * 4 + quad) ^ (l15 & 7)) << 3));
                o[nt] = __builtin_amdgcn_mfma_f32_16x16x32_bf16(pf[kc], vf, o[nt], 0, 0, 0);
            }
        }
        __builtin_amdgcn_s_setprio(0);

        if (more) {
#pragma unroll
            for (int j = 0; j < 8; j++) {
                u32 wv = ((u32)(u16)v0[j]) | (((u32)(u16)v1[j]) << 16);
                *(u32*)((char*)Vs[nxt] + (size_t)(vd8 * 8 + j) * 128
                        + ((((vkv >> 3) ^ j)) << 4) + ((vkv * 2) & 15)) = wv;
            }
        }
        __syncthreads();
        cur = nxt;
    }

    const size_t ub = (size_t)b * N * 1024;
#pragma unroll
    for (int r = 0; r < 4; r++) {
        float lb = __shfl(lrow, quad * 4 + r, 64);
        float inv = 1.f / lb;
        const size_t row = qb * 128 + wave * 16 + quad * 4 + r;
#pragma unroll
        for (int nt = 0; nt < 8; nt++) {
            const size_t idx = ub + row * 1024 + h * 128 + nt * 16 + l15;
            U[idx] = f2bf(X[idx] + o[nt][r] * inv);
        }
    }
}

// ---------------- launch ----------------
// 10 launches. NON-ALIASING workspace layout (r9 bug: crq/qres at w+32MB
// collided with qt; q output corrupted). Live-range-verified layout:
//   @0        pmean (512K) + gates (64K)
//   @1MB      cWt 6MB | @7MB cWo 2MB
//   @9437184  qt 24MB / vt 48MB            (ends 59768832)
//   @34603008 crq/qres 8MB                 (starts exactly at qt end;
//                                           crq dead before qres written;
//                                           vt overwrites later, crq dead)
//   @59768832 crv/vres 16MB                (starts exactly at vt end;
//                                           crv dead after gemmVt, vres after)
// peak 73.0 MB. Timeline audit: every region's writer precedes its readers
// and no concurrently-live pair overlaps.

extern "C" void kernel_launch(void* const* d_in, const int* in_sizes, int n_in,
                              void* d_out, int out_size, void* d_ws, size_t ws_size,
                              hipStream_t stream) {
    (void)in_sizes; (void)n_in; (void)out_size; (void)ws_size;
    const float* v   = (const float*)d_in[0];
    const float* q   = (const float*)d_in[1];
    const float* Wg_v4q = (const float*)d_in[2];
    const float* bg_v4q = (const float*)d_in[3];
    const float* Wg_q4v = (const float*)d_in[4];
    const float* bg_q4v = (const float*)d_in[5];
    const float* Wv  = (const float*)d_in[6];
    const float* bv  = (const float*)d_in[7];
    const float* Wq  = (const float*)d_in[8];
    const float* bq  = (const float*)d_in[9];
    const float* Wvo = (const float*)d_in[10];
    const float* bvo = (const float*)d_in[11];
    const float* Wqo = (const float*)d_in[12];
    const float* bqo = (const float*)d_in[13];
    float* out = (float*)d_out;                     // [v: 8388608][q: 4194304] f32

    char* w = (char*)d_ws;
    float* pmean = (float*)(w + 0);                 // 8 x 16384 f32 = 512 KB
    float* gv4q  = (float*)(w + 524288);            // 32 KB
    float* gq4v  = (float*)(w + 557056);            // 32 KB
    u16* cWt  = (u16*)(w + 1048576);                // 6 MB (trans weight bf16)
    u16* cWo  = (u16*)(w + 7340032);                // 2 MB (proj weight bf16)
    u16* tReg = (u16*)(w + 9437184);                // qt 24MB / vt 48MB
    u16* crq  = (u16*)(w + 34603008);               // 8 MB  (also qres)
    u16* crv  = (u16*)(w + 59768832);               // 16 MB (also vres)

    u16* qt   = tReg;
    u16* vt   = tReg;
    u16* qres = crq;
    u16* vres = crv;

    // fused stats + act cvt, then both gates
    meancvt_kernel<<<dim3(64, 8), 256, 0, stream>>>(v, q, crv, crq, pmean);
    gate_kernel<<<4096, 256, 0, stream>>>(pmean, Wg_v4q, bg_v4q, gv4q,
                                          Wg_q4v, bg_q4v, gq4v);

    // ---- q phase ----
    wcvt_kernel<<<2048, 256, 0, stream>>>(Wq, Wqo, cWt, cWo);
    gemm_bt_kernel<<<dim3(24, 32), 256, 0, stream>>>(crq, cWt, bq, gv4q, qt, nullptr,
                                                     4096, 3072, 1024, 512, 2048);
    attn_kernel<<<dim3(4, 64), 512, 0, stream>>>(qt, q, qres, 512);
    gemm_bt_kernel<<<dim3(8, 32), 256, 0, stream>>>(qres, cWo, bqo, nullptr, nullptr,
                                                    out + 8388608, 4096, 1024, 1024, 512, 0);

    // ---- v phase ----
    wcvt_kernel<<<2048, 256, 0, stream>>>(Wv, Wvo, cWt, cWo);
    gemm_bt_kernel<<<dim3(24, 64), 256, 0, stream>>>(crv, cWt, bv, gq4v, vt, nullptr,
                                                     8192, 3072, 1024, 1024, 2048);
    attn_kernel<<<dim3(8, 64), 512, 0, stream>>>(vt, v, vres, 1024);
    gemm_bt_kernel<<<dim3(8, 64), 256, 0, stream>>>(vres, cWo, bvo, nullptr, nullptr,
                                                    out, 8192, 1024, 1024, 1024, 0);
}